// Round 9
// baseline (9481.708 us; speedup 1.0000x reference)
//
#include <hip/hip_runtime.h>

// LSTM T=1024 B=16 I=H=1024 L=2. f32 in/out, bf16 MFMA internally.
// Round 14: FLAGLESS ring — tag-embedded data.
//  - r13 witness: removing the whole consumer staging hop was FLAT -> the
//    bottleneck is the flag protocol itself (drain + flag store + 1024 waves
//    polling the same 256B of flags = serialized RTs + LLC hot-line queuing).
//  - Publish h as atomic u64 granules (tag<<32 | data). Consumers poll their
//    own K-slice granules; tags==slot => data valid in the SAME u64 (8B
//    atomicity). No flags, no drain, no separate data load, no tail barrier
//    (lds_part double-buffered by t&1).
//  - hist0 slots 1..1024 (tagged, 64KB) overlay xpack+old-hist0 (pack_x
//    rewrites 1..511 each run; init zeroes 512..1024). h1(t+1) (tagged, 64KB)
//    overlays first half of dead gx slot t (gx_gemm rewrites gxbuf each run).
//  - Numerics identical to r13. Workspace 235,077,632 B (< proven 235.2MB).

#define T_STEPS 1024
#define TQ 16        // t-chunks for gx gemm grid

typedef unsigned short u16;
typedef unsigned long long u64;
typedef __attribute__((ext_vector_type(8))) __bf16 bf16x8;      // 8 bf16 = 4 VGPR
typedef __attribute__((ext_vector_type(4))) float float4v;      // MFMA C/D + f32 loads
typedef __attribute__((ext_vector_type(4))) unsigned short ushort4v;
typedef __attribute__((ext_vector_type(8))) unsigned short ushort8;
typedef __attribute__((ext_vector_type(4))) unsigned uint4v;

__device__ __forceinline__ float bf2f(u16 h) {
    unsigned u = ((unsigned)h) << 16;
    return __builtin_bit_cast(float, u);
}
__device__ __forceinline__ u16 f2bf(float f) {
    unsigned u = __builtin_bit_cast(unsigned, f);
    u += 0x7fff + ((u >> 16) & 1);   // RNE
    return (u16)(u >> 16);
}

__device__ __forceinline__ float4v mfma16(bf16x8 a, bf16x8 b, float4v c) {
    return __builtin_amdgcn_mfma_f32_16x16x32_bf16(a, b, c, 0, 0, 0);
}
__device__ __forceinline__ u64 aload64(const u64* p) {
    return __hip_atomic_load(p, __ATOMIC_RELAXED, __HIP_MEMORY_SCOPE_AGENT);
}
__device__ __forceinline__ void astore64(u64* p, u64 v) {
    __hip_atomic_store(p, v, __ATOMIC_RELAXED, __HIP_MEMORY_SCOPE_AGENT);
}
// opaque pin: value can no longer be rematerialized from its defining load
__device__ __forceinline__ void pin(bf16x8& v) {
    asm volatile("" : "+v"(v));
}
// cached 16B global->LDS (producer-dispatch-ordered data: xpack in gx_gemm)
__device__ __forceinline__ void gld_lds16c(const void* g, void* l) {
    __builtin_amdgcn_global_load_lds(
        (const __attribute__((address_space(1))) unsigned*)g,
        (__attribute__((address_space(3))) unsigned*)l, 16, 0, 0);
}

// ---------------------------------------------------------------- init
// zero [ws+67,108,864 , ws+100,859,904): hist0 tagged slots 512..1024 + z0 + z1
__global__ void init_zero(u64* __restrict__ z) {
    const size_t N = 4218880;   // 33,751,040 B / 8
    size_t i = (size_t)blockIdx.x * 256 + threadIdx.x;
    for (size_t k = i; k < N; k += (size_t)256 * 256) z[k] = 0ull;
}

// ---------------------------------------------------------------- pack
// f32 -> bf16 A/B-frag tiles. dst[tile][kc][lane][8] =
//   src[rowbase+lane%16][kc*32+(lane/16)*8+j]
__device__ __forceinline__ void pack_one(const float* src, u16* dst, int tile, int rowbase) {
    int tid = threadIdx.x;
    ushort8* d = (ushort8*)dst;
#pragma unroll
    for (int it = 0; it < 8; ++it) {
        int c = tid + it * 256;
        int kc = c >> 6, lane = c & 63;
        const float4v* s4 = (const float4v*)(src + (((long)(rowbase + (lane & 15))) << 10)
                                                 + (kc << 5) + ((lane >> 4) << 3));
        float4v lo = s4[0], hi = s4[1];
        ushort8 o;
        o[0] = f2bf(lo[0]); o[1] = f2bf(lo[1]); o[2] = f2bf(lo[2]); o[3] = f2bf(lo[3]);
        o[4] = f2bf(hi[0]); o[5] = f2bf(hi[1]); o[6] = f2bf(hi[2]); o[7] = f2bf(hi[3]);
        d[tile * 2048 + c] = o;
    }
}

__global__ void pack_x(const float* __restrict__ src, u16* __restrict__ dst) {
    pack_one(src, dst, blockIdx.x, blockIdx.x << 4);   // rowbase = t*16
}

// 4 weight matrices in one dispatch: grid 1024, which = blockIdx>>8
__global__ void pack_w(const float* __restrict__ w0, const float* __restrict__ w1,
                       const float* __restrict__ w2, const float* __restrict__ w3,
                       u16* __restrict__ d0, u16* __restrict__ d1,
                       u16* __restrict__ d2, u16* __restrict__ d3) {
    int which = blockIdx.x >> 8, tile = blockIdx.x & 255;
    const float* s = (which == 0) ? w0 : (which == 1) ? w1 : (which == 2) ? w2 : w3;
    u16* d = (which == 0) ? d0 : (which == 1) ? d1 : (which == 2) ? d2 : d3;
    int rowbase = ((tile & 3) << 10) + ((tile >> 2) << 4);
    pack_one(s, d, tile, rowbase);
}

// ---------------------------------------------------------------- gx gemm (layer 0)
__global__ __launch_bounds__(256, 1) void gx_gemm(
        const u16* __restrict__ xp, const bf16x8* __restrict__ wp,
        const float* __restrict__ bih, const float* __restrict__ bhh,
        u16* __restrict__ gx) {
    __shared__ u64 abuf[4096];              // 32 KB
    __shared__ float4v part[4][4][64];      // 16 KB  [kslice][gate][lane]
    int blk = blockIdx.x, tq = blockIdx.y;
    int tid = threadIdx.x, w = tid >> 6, L = tid & 63;
    int gc = (w << 10) + (blk << 4) + (L & 15);
    float bsum = bih[gc] + bhh[gc];

    bf16x8 wf[32];   // [gate][k] for this wave's K-slice
#pragma unroll
    for (int g = 0; g < 4; ++g) {
        const bf16x8* wpt = wp + (blk * 4 + g) * 2048 + (w * 8) * 64 + L;
#pragma unroll
        for (int k = 0; k < 8; ++k) wf[g * 8 + k] = wpt[k * 64];
    }
#pragma unroll
    for (int i = 0; i < 32; ++i) pin(wf[i]);
    const bf16x8* hp = (const bf16x8*)abuf;

    const int tch = T_STEPS / TQ;
    for (int tt = 0; tt < tch; ++tt) {
        int t = tq * tch + tt;
        const char* src = (const char*)xp + ((size_t)t << 15) + (w << 13) + (L << 4);
        char* dst = (char*)abuf + (w << 13);
#pragma unroll
        for (int i = 0; i < 8; ++i) gld_lds16c(src + i * 1024, dst + i * 1024);
        __builtin_amdgcn_s_waitcnt(0);          // own stage done (own quarter only)
        __builtin_amdgcn_sched_barrier(0);

        float4v acc[4];
#pragma unroll
        for (int g = 0; g < 4; ++g) acc[g] = float4v{0.f, 0.f, 0.f, 0.f};
#pragma unroll
        for (int k = 0; k < 8; ++k) {
            bf16x8 a = hp[(8 * w + k) * 64 + L];
#pragma unroll
            for (int g = 0; g < 4; ++g) acc[g] = mfma16(a, wf[g * 8 + k], acc[g]);
        }
#pragma unroll
        for (int g = 0; g < 4; ++g) part[w][g][L] = acc[g];
        __syncthreads();
        float4v s = part[0][w][L] + part[1][w][L] + part[2][w][L] + part[3][w][L];
        ushort4v o;
#pragma unroll
        for (int r = 0; r < 4; ++r) o[r] = f2bf(s[r] + bsum);
        ((ushort4v*)gx)[((t * 64 + blk) * 4 + w) * 64 + L] = o;
        __syncthreads();    // part reusable next iteration
    }
}

// ---------------------------------------------------------------- fused pipelined scan
// 512 threads, 8 waves, 64+64 blocks. Tagged-granule ring (no flags):
//  hist0 slot s (s=1..1024, tagged 64KB) at hist0t + (s-1)*65536, tag = s.
//  h1 slot s  (s=1..1024, tagged 64KB) at gxb + (s-1)*131072, tag = s.
//  granule = u64 (lo = 2x bf16 data, hi = tag). Consumer polls its own
//  K-slice granules; tag match => data valid (8B atomic store).
__global__ __launch_bounds__(512, 1)
void lstm_scan2(
        const u16* __restrict__ gx0,     // gxbuf (C-frag gates_x, both biases)
        const bf16x8* __restrict__ wpHh0,
        const bf16x8* __restrict__ wpIh1, const bf16x8* __restrict__ wpHh1,
        const float* __restrict__ bih1, const float* __restrict__ bhh1,
        char* hist0t,                    // tagged h0 slots 1..1024
        char* z0,                        // zeroed tagged h0 slot 0
        char* z1,                        // zeroed tagged h1 slot 0
        char* gxb,                       // gxbuf base (h1 tagged slots overlay)
        float* outbase) {                // d_out
    __shared__ float4v lds_part[2][8][4][64];  // 64 KB double-buffered
    __shared__ float4v lds_g[4][64];           // 4 KB

    int tid = threadIdx.x, w = tid >> 6, L = tid & 63;
    int m = tid >> 4, j = tid & 15;            // roles valid for tid<256
    int Lc = ((m >> 2) << 4) | j, rr = m & 3;
    int layer = (blockIdx.x >= 64);
    int blk = blockIdx.x & 63;
    int hcol = (blk << 4) + j;
    int kcw = hcol >> 5, laneg = (hcol >> 3) & 3, jj = hcol & 7;
    int hwoff32 = ((kcw * 64 + m + (laneg << 4)) << 2) + (jj >> 1);
    float* fH = outbase + 16777216 + (layer ? 16384 : 0);
    float* fC = outbase + 16777216 + 32768 + (layer ? 16384 : 0);
    float c = 0.f;

    if (!layer) {
        // ---------------- layer 0: K=1024, wave w owns kc [4w,4w+4) ----------------
        bf16x8 wf[16];   // [gate][k], 64 VGPR — resident
#pragma unroll
        for (int g = 0; g < 4; ++g) {
            const bf16x8* wsrc = wpHh0 + (blk * 4 + g) * 2048 + (4 * w) * 64 + L;
#pragma unroll
            for (int k = 0; k < 4; ++k) wf[g * 4 + k] = wsrc[k * 64];
        }
#pragma unroll
        for (int i = 0; i < 16; ++i) pin(wf[i]);
        int gbase = (w << 10) + (L << 2);

        for (int t = 0; t < T_STEPS; ++t) {
            ushort4v gxv = {0, 0, 0, 0};
            if (w < 4) gxv = ((const ushort4v*)gx0)[((t * 64 + blk) * 4 + w) * 64 + L];

            // acquire h0(t): poll own 16 granules until all tags == t
            const u64* sb = (t == 0) ? (const u64*)z0
                                     : (const u64*)(hist0t + ((size_t)(t - 1) << 16));
            u64 d[16];
            if (t > 0) {
                u64 tag = (u64)(unsigned)t;
                u64 bad;
                do {
#pragma unroll
                    for (int k = 0; k < 4; ++k)
#pragma unroll
                        for (int q = 0; q < 4; ++q)
                            d[k * 4 + q] = aload64(sb + gbase + 256 * k + q);
                    bad = 0;
#pragma unroll
                    for (int i = 0; i < 16; ++i) bad |= (d[i] >> 32) ^ tag;
                } while (__ballot(bad == 0ull) != ~0ull);
            } else {
#pragma unroll
                for (int k = 0; k < 4; ++k)
#pragma unroll
                    for (int q = 0; q < 4; ++q)
                        d[k * 4 + q] = aload64(sb + gbase + 256 * k + q);
            }
            bf16x8 a[4];
#pragma unroll
            for (int k = 0; k < 4; ++k) {
                uint4v v = { (unsigned)d[4 * k], (unsigned)d[4 * k + 1],
                             (unsigned)d[4 * k + 2], (unsigned)d[4 * k + 3] };
                a[k] = __builtin_bit_cast(bf16x8, v);
            }

            float4v acc[4];
#pragma unroll
            for (int g = 0; g < 4; ++g) acc[g] = float4v{0.f, 0.f, 0.f, 0.f};
#pragma unroll
            for (int k = 0; k < 4; ++k)
#pragma unroll
                for (int g = 0; g < 4; ++g) acc[g] = mfma16(a[k], wf[g * 4 + k], acc[g]);
#pragma unroll
            for (int g = 0; g < 4; ++g) lds_part[t & 1][w][g][L] = acc[g];
            __syncthreads();

            if (w < 4) {   // reduce: wave w = gate w
                float4v s = lds_part[t & 1][0][w][L];
#pragma unroll
                for (int ks = 1; ks < 8; ++ks) s = s + lds_part[t & 1][ks][w][L];
                float4v g4;
#pragma unroll
                for (int r = 0; r < 4; ++r) g4[r] = s[r] + bf2f(gxv[r]);
                lds_g[w][L] = g4;
            }
            __syncthreads();

            if (tid < 256) {
                float gi = lds_g[0][Lc][rr], gf = lds_g[1][Lc][rr];
                float gg = lds_g[2][Lc][rr], go = lds_g[3][Lc][rr];
                float iv = 1.f / (1.f + __expf(-gi));
                float fv = 1.f / (1.f + __expf(-gf));
                float gv = 1.f - 2.f / (1.f + __expf(2.f * gg));
                float ov = 1.f / (1.f + __expf(-go));
                c = fv * c + iv * gv;
                float h = ov * (1.f - 2.f / (1.f + __expf(2.f * c)));
                unsigned hb = f2bf(h);
                unsigned other = (unsigned)__shfl_xor((int)hb, 1);
                if (!(tid & 1))   // publish tagged granule: h0(t+1), tag t+1
                    astore64((u64*)(hist0t + ((size_t)t << 16) + ((size_t)hwoff32 << 3)),
                             (u64)(hb | (other << 16)) | ((u64)(unsigned)(t + 1) << 32));
                if (t == T_STEPS - 1) {
                    fH[(m << 10) + hcol] = h;
                    fC[(m << 10) + hcol] = c;
                }
            }
            // no tail barrier: lds_part double-buffered; lds_g protected by the
            // two barriers of the next iteration.
        }
    } else {
        // ---------------- layer 1: concat K=2048, wave w owns 8 kc ----------------
        bf16x8 wf[32];   // [gate][k] (128 VGPR; RA may stream — r13 baseline)
#pragma unroll
        for (int g = 0; g < 4; ++g) {
            const bf16x8* wsrc = (w < 4)
                ? (wpIh1 + (blk * 4 + g) * 2048 + (8 * w) * 64 + L)
                : (wpHh1 + (blk * 4 + g) * 2048 + (8 * (w - 4)) * 64 + L);
#pragma unroll
            for (int k = 0; k < 8; ++k) wf[g * 8 + k] = wsrc[k * 64];
        }
#pragma unroll
        for (int i = 0; i < 32; ++i) pin(wf[i]);
        int gc = (w << 10) + (blk << 4) + (L & 15);
        float bsum = (w < 4) ? (bih1[gc] + bhh1[gc]) : 0.f;
        int gbase = ((w & 3) << 11) + (L << 2);

        for (int t = 0; t < T_STEPS; ++t) {
            // acquire: A-half (w<4) needs out0(t)=h0(t+1) [tag t+1];
            //          B-half needs h1(t) [tag t; t=0 -> zeroed slot]
            const u64* sb;
            u64 tag;
            if (w < 4) { sb = (const u64*)(hist0t + ((size_t)t << 16)); tag = (u64)(unsigned)(t + 1); }
            else {
                sb = (t == 0) ? (const u64*)z1
                              : (const u64*)(gxb + ((size_t)(t - 1) << 17));
                tag = (u64)(unsigned)t;
            }
            u64 d[32];
            if (w < 4 || t > 0) {
                u64 bad;
                do {
#pragma unroll
                    for (int k = 0; k < 8; ++k)
#pragma unroll
                        for (int q = 0; q < 4; ++q)
                            d[k * 4 + q] = aload64(sb + gbase + 256 * k + q);
                    bad = 0;
#pragma unroll
                    for (int i = 0; i < 32; ++i) bad |= (d[i] >> 32) ^ tag;
                } while (__ballot(bad == 0ull) != ~0ull);
            } else {
#pragma unroll
                for (int k = 0; k < 8; ++k)
#pragma unroll
                    for (int q = 0; q < 4; ++q)
                        d[k * 4 + q] = aload64(sb + gbase + 256 * k + q);
            }
            bf16x8 a[8];
#pragma unroll
            for (int k = 0; k < 8; ++k) {
                uint4v v = { (unsigned)d[4 * k], (unsigned)d[4 * k + 1],
                             (unsigned)d[4 * k + 2], (unsigned)d[4 * k + 3] };
                a[k] = __builtin_bit_cast(bf16x8, v);
            }

            float4v acc[4];
#pragma unroll
            for (int g = 0; g < 4; ++g) acc[g] = float4v{0.f, 0.f, 0.f, 0.f};
#pragma unroll
            for (int k = 0; k < 8; ++k)
#pragma unroll
                for (int g = 0; g < 4; ++g) acc[g] = mfma16(a[k], wf[g * 8 + k], acc[g]);
#pragma unroll
            for (int g = 0; g < 4; ++g) lds_part[t & 1][w][g][L] = acc[g];
            __syncthreads();

            if (w < 4) {   // reduce: wave w = gate w
                float4v s = lds_part[t & 1][0][w][L];
#pragma unroll
                for (int ks = 1; ks < 8; ++ks) s = s + lds_part[t & 1][ks][w][L];
                float4v g4;
#pragma unroll
                for (int r = 0; r < 4; ++r) g4[r] = s[r] + bsum;
                lds_g[w][L] = g4;
            }
            __syncthreads();

            float h = 0.f;
            if (tid < 256) {
                float gi = lds_g[0][Lc][rr], gf = lds_g[1][Lc][rr];
                float gg = lds_g[2][Lc][rr], go = lds_g[3][Lc][rr];
                float iv = 1.f / (1.f + __expf(-gi));
                float fv = 1.f / (1.f + __expf(-gf));
                float gv = 1.f - 2.f / (1.f + __expf(2.f * gg));
                float ov = 1.f / (1.f + __expf(-go));
                c = fv * c + iv * gv;
                h = ov * (1.f - 2.f / (1.f + __expf(2.f * c)));
                unsigned hb = f2bf(h);
                unsigned other = (unsigned)__shfl_xor((int)hb, 1);
                if (!(tid & 1))   // publish tagged granule: h1(t+1), tag t+1
                    astore64((u64*)(gxb + ((size_t)t << 17) + ((size_t)hwoff32 << 3)),
                             (u64)(hb | (other << 16)) | ((u64)(unsigned)(t + 1) << 32));
                outbase[(t << 14) + (m << 10) + hcol] = h;
                if (t == T_STEPS - 1) {
                    fH[(m << 10) + hcol] = h;
                    fC[(m << 10) + hcol] = c;
                }
            }
        }
    }
}

// ---------------------------------------------------------------- launch
extern "C" void kernel_launch(void* const* d_in, const int* in_sizes, int n_in,
                              void* d_out, int out_size, void* d_ws, size_t ws_size,
                              hipStream_t stream) {
    const float* x    = (const float*)d_in[0];
    const float* Wih0 = (const float*)d_in[1];
    const float* bih0 = (const float*)d_in[2];
    const float* Whh0 = (const float*)d_in[3];
    const float* bhh0 = (const float*)d_in[4];
    const float* Wih1 = (const float*)d_in[5];
    const float* bih1 = (const float*)d_in[6];
    const float* Whh1 = (const float*)d_in[7];
    const float* bhh1 = (const float*)d_in[8];
    float* out = (float*)d_out;

    char* ws = (char*)d_ws;
    u16* wpIh0 = (u16*)(ws + 0);            //  8,388,608
    u16* wpHh0 = (u16*)(ws + 8388608);      //  8,388,608
    u16* wpIh1 = (u16*)(ws + 16777216);     //  8,388,608
    u16* wpHh1 = (u16*)(ws + 25165824);     //  8,388,608
    char* hist0t = ws + 33554432;           // tagged h0 slots 1..1024 (64KB each)
                                            //  [33,554,432 , 100,728,832)
    u16* xpack = (u16*)(ws + 33554432);     // pack_x dst = hist0t slots 1..511
    u64* tailz = (u64*)(ws + 67108864);     // init zeroes [67,108,864 , 100,859,904)
    char* z0   = ws + 100728832;            // 65,536 (tagged h0 slot 0, zeroed)
    char* z1   = ws + 100794368;            // 65,536 (tagged h1 slot 0, zeroed)
    char* gxb  = ws + 100859904;            // 134,217,728 -> ends 235,077,632

    init_zero<<<dim3(256), dim3(256), 0, stream>>>(tailz);
    pack_w<<<dim3(1024), dim3(256), 0, stream>>>(Wih0, Whh0, Wih1, Whh1,
                                                 wpIh0, wpHh0, wpIh1, wpHh1);
    pack_x<<<dim3(1024), dim3(256), 0, stream>>>(x, xpack);
    gx_gemm<<<dim3(64, TQ), dim3(256), 0, stream>>>(
        xpack, (const bf16x8*)wpIh0, bih0, bhh0, (u16*)gxb);
    lstm_scan2<<<dim3(128), dim3(512), 0, stream>>>(
        (const u16*)gxb, (const bf16x8*)wpHh0, (const bf16x8*)wpIh1,
        (const bf16x8*)wpHh1, bih1, bhh1, hist0t, z0, z1, gxb, out);
}